// Round 12
// baseline (14855.479 us; speedup 1.0000x reference)
//
#include <hip/hip_runtime.h>
#include <math.h>

#define T_STEPS 512     // !!! sequence length is 512 (C=20 is num classes)
#define BATCH   128
#define HID     256
#define NCLS    20
#define G4      1024    // 4*HID
#define XPAD    260     // LDS row pad: bank = r*4+k%32, conflict-free

// ---------------------------------------------------------------------------
// One LSTM timestep, both directions. grid (rowtile=16, unittile=8, dir=2),
// block 256. Per block: 8 batch rows x 32 hidden units (=128 gate-cols).
// Phase 1: 4 waves = 4 gates; thread (g,r,q) computes float4 of z.
// Phase 2: thread (r,j) fuses gates -> c,h update.
// ---------------------------------------------------------------------------
__global__ __launch_bounds__(256) void lstm_step_v12(
    const int*   __restrict__ tokens,
    const float* __restrict__ emb_table,
    const float* __restrict__ W_f, const float* __restrict__ U_f, const float* __restrict__ b_f,
    const float* __restrict__ W_b, const float* __restrict__ U_b, const float* __restrict__ b_b,
    const float* __restrict__ h_in, float* __restrict__ h_out,
    float* __restrict__ c_state, int step)
{
    const int rt  = blockIdx.x;       // rows rt*8 .. rt*8+7
    const int ut  = blockIdx.y;       // units ut*32 .. ut*32+31
    const int dir = blockIdx.z;
    const int tid = threadIdx.x;

    const float* __restrict__ W  = dir ? W_b : W_f;
    const float* __restrict__ U  = dir ? U_b : U_f;
    const float* __restrict__ bs = dir ? b_b : b_f;

    __shared__ int   tok[8];
    __shared__ float xs[8][XPAD];
    __shared__ float hs[8][XPAD];
    __shared__ float zs[4][8][32];

    const int tt = dir ? (T_STEPS - 1 - step) : step;
    if (tid < 8) {
        int token = tokens[(rt * 8 + tid) * T_STEPS + tt];
        tok[tid] = (token < 0) ? 0 : (token > 49999 ? 49999 : token);
    }
    __syncthreads();

    for (int i = tid; i < 8 * 256; i += 256) {
        int r = i >> 8, k = i & 255;
        xs[r][k] = emb_table[(size_t)tok[r] * 256 + k];
        hs[r][k] = h_in[((size_t)dir * BATCH + rt * 8 + r) * HID + k];
    }
    __syncthreads();

    // thread -> (gate g, row r, quad q); cols = g*256 + ut*32 + q*4 .. +3
    const int g = tid >> 6;
    const int r = (tid >> 3) & 7;
    const int q = tid & 7;
    const int col = g * 256 + ut * 32 + q * 4;

    const float4* __restrict__ W4 = (const float4*)(W + col);
    const float4* __restrict__ U4 = (const float4*)(U + col);
    float4 acc = *(const float4*)(bs + col);   // bias folded into acc init

    #pragma unroll 4
    for (int k = 0; k < 256; ++k) {
        float xv = xs[r][k];
        float hv = hs[r][k];
        float4 w = W4[(size_t)k * 256];        // W[k][col..col+3]
        float4 u = U4[(size_t)k * 256];
        acc.x = fmaf(xv, w.x, acc.x); acc.y = fmaf(xv, w.y, acc.y);
        acc.z = fmaf(xv, w.z, acc.z); acc.w = fmaf(xv, w.w, acc.w);
        acc.x = fmaf(hv, u.x, acc.x); acc.y = fmaf(hv, u.y, acc.y);
        acc.z = fmaf(hv, u.z, acc.z); acc.w = fmaf(hv, u.w, acc.w);
    }
    *(float4*)&zs[g][r][q * 4] = acc;
    __syncthreads();

    {
        const int r2 = tid >> 5;          // 0..7
        const int j2 = tid & 31;          // 0..31
        float zi = zs[0][r2][j2];
        float zf = zs[1][r2][j2];
        float zg = zs[2][r2][j2];
        float zo = zs[3][r2][j2];
        float si = 1.0f / (1.0f + expf(-zi));
        float sf = 1.0f / (1.0f + expf(-zf));
        float tg = tanhf(zg);
        float so = 1.0f / (1.0f + expf(-zo));
        size_t idx = ((size_t)dir * BATCH + rt * 8 + r2) * HID + ut * 32 + j2;
        float cv = fmaf(sf, c_state[idx], si * tg);
        c_state[idx] = cv;
        h_out[idx] = so * tanhf(cv);
    }
}

// ---------------------------------------------------------------------------
// Dense + softmax (f32): one block per batch row.
// ---------------------------------------------------------------------------
__global__ __launch_bounds__(64) void dense_softmax_v12(
    const float* __restrict__ h_final,     // [2][BATCH][HID]
    const float* __restrict__ W_d, const float* __restrict__ b_d,
    float* __restrict__ out)
{
    const int rrow = blockIdx.x;
    const int cth  = threadIdx.x;
    __shared__ float lg[NCLS];

    if (cth < NCLS) {
        const float* hf = h_final + (size_t)rrow * HID;
        const float* hb = h_final + ((size_t)BATCH + rrow) * HID;
        float s = b_d[cth];
        for (int k = 0; k < HID; ++k)
            s = fmaf(hf[k], W_d[k * NCLS + cth], s);
        for (int k = 0; k < HID; ++k)
            s = fmaf(hb[k], W_d[(HID + k) * NCLS + cth], s);
        lg[cth] = s;
    }
    __syncthreads();

    if (cth == 0) {
        float m = lg[0];
        for (int c = 1; c < NCLS; ++c) m = fmaxf(m, lg[c]);
        float e[NCLS];
        float ssum = 0.0f;
        for (int c = 0; c < NCLS; ++c) { e[c] = expf(lg[c] - m); ssum += e[c]; }
        float inv = 1.0f / ssum;
        for (int c = 0; c < NCLS; ++c)
            out[rrow * NCLS + c] = e[c] * inv;
    }
}

extern "C" void kernel_launch(void* const* d_in, const int* in_sizes, int n_in,
                              void* d_out, int out_size, void* d_ws, size_t ws_size,
                              hipStream_t stream)
{
    const int*   tokens = (const int*)d_in[0];
    const float* emb    = (const float*)d_in[1];
    const float* W_f    = (const float*)d_in[2];
    const float* U_f    = (const float*)d_in[3];
    const float* b_f    = (const float*)d_in[4];
    const float* W_b    = (const float*)d_in[5];
    const float* U_b    = (const float*)d_in[6];
    const float* b_b    = (const float*)d_in[7];
    const float* W_d    = (const float*)d_in[8];
    const float* b_d    = (const float*)d_in[9];
    float* out = (float*)d_out;

    const size_t SLOT = (size_t)2 * BATCH * HID;   // 65536 floats
    float* hbuf0 = (float*)d_ws;          // zeroed (h0)
    float* cbuf  = hbuf0 + SLOT;          // zeroed (c0), updated in place
    float* hbuf1 = cbuf + SLOT;

    // zero h0 and c0 every call (harness does not re-poison between replays)
    hipMemsetAsync(hbuf0, 0, 2 * SLOT * sizeof(float), stream);

    float* hin  = hbuf0;
    float* hout = hbuf1;
    for (int s = 0; s < T_STEPS; ++s) {
        lstm_step_v12<<<dim3(16, 8, 2), 256, 0, stream>>>(
            tokens, emb, W_f, U_f, b_f, W_b, U_b, b_b, hin, hout, cbuf, s);
        float* tmp = hin; hin = hout; hout = tmp;
    }
    // after 512 swaps (even), final h is in hbuf0 == hin

    dense_softmax_v12<<<dim3(BATCH), 64, 0, stream>>>(hin, W_d, b_d, out);
}

// Round 13
// 6051.409 us; speedup vs baseline: 2.4549x; 2.4549x over previous
//
#include <hip/hip_runtime.h>
#include <math.h>

#define T_SEQ  512
#define BATCH  128
#define HID    256
#define NCLS   20
#define G4     1024   // 4*HID

// ---------------------------------------------------------------------------
// Kernel A: batched input projection. xw[dir][s][b][col] = emb[token]@W + bias
// token = tokens[b][chunk0+s] (fwd) / tokens[b][511-(chunk0+s)] (bwd).
// grid (mtiles = chunk*128/32, ntiles = 8, dir = 2), block 256.
// Tiles: 32 rows (m = s*128+b) x 128 cols, K=256. LDS 48.1 KB (< 64 KB!).
// ---------------------------------------------------------------------------
__global__ __launch_bounds__(256) void xw_gemm_v13(
    const int*   __restrict__ tokens,
    const float* __restrict__ emb_table,
    const float* __restrict__ W_f, const float* __restrict__ b_f,
    const float* __restrict__ W_b, const float* __restrict__ b_b,
    float* __restrict__ xw, int chunk0, int chunk_len)
{
    const int dir = blockIdx.z;
    const float* __restrict__ W    = dir ? W_b : W_f;
    const float* __restrict__ bias = dir ? b_b : b_f;
    const int mtile = blockIdx.x;
    const int ntile = blockIdx.y;
    const int tid = threadIdx.x;

    __shared__ float At[256][32];   // A^T [k][m'] 32 KB
    __shared__ float Bs[32][128];   // W chunk [k][c] 16 KB
    __shared__ int   tok[32];

    if (tid < 32) {
        int m = mtile * 32 + tid;
        int s_local = m >> 7;
        int b = m & 127;
        int tt = chunk0 + s_local;
        if (dir) tt = T_SEQ - 1 - tt;
        int token = tokens[b * T_SEQ + tt];
        tok[tid] = token < 0 ? 0 : (token > 49999 ? 49999 : token);
    }
    __syncthreads();

    {   // gather 32 emb rows, store transposed
        int r = tid >> 3, c8 = tid & 7;
        const float4* src = (const float4*)(emb_table + (size_t)tok[r] * 256);
        #pragma unroll
        for (int i = 0; i < 8; ++i) {
            int c4 = c8 + i * 8;
            float4 v = src[c4];
            int k0 = c4 * 4;
            At[k0 + 0][r] = v.x; At[k0 + 1][r] = v.y;
            At[k0 + 2][r] = v.z; At[k0 + 3][r] = v.w;
        }
    }

    const int r0 = (tid >> 6) * 8;   // wave-uniform row group
    const int col0 = tid & 63;
    float acc0[8], acc1[8];
    {
        float bv0 = bias[ntile * 128 + col0];
        float bv1 = bias[ntile * 128 + col0 + 64];
        #pragma unroll
        for (int i = 0; i < 8; ++i) { acc0[i] = bv0; acc1[i] = bv1; }
    }

    for (int kc = 0; kc < 8; ++kc) {
        __syncthreads();
        #pragma unroll
        for (int i = 0; i < 4; ++i) {
            int idx = tid + i * 256;
            int row = idx >> 5, c4 = idx & 31;
            *(float4*)&Bs[row][c4 * 4] =
                *(const float4*)&W[(size_t)(kc * 32 + row) * G4 + ntile * 128 + c4 * 4];
        }
        __syncthreads();
        #pragma unroll 8
        for (int k = 0; k < 32; ++k) {
            float4 a0 = *(const float4*)&At[kc * 32 + k][r0];      // broadcast
            float4 a1 = *(const float4*)&At[kc * 32 + k][r0 + 4];
            float bb0 = Bs[k][col0];
            float bb1 = Bs[k][col0 + 64];
            acc0[0] = fmaf(a0.x, bb0, acc0[0]); acc1[0] = fmaf(a0.x, bb1, acc1[0]);
            acc0[1] = fmaf(a0.y, bb0, acc0[1]); acc1[1] = fmaf(a0.y, bb1, acc1[1]);
            acc0[2] = fmaf(a0.z, bb0, acc0[2]); acc1[2] = fmaf(a0.z, bb1, acc1[2]);
            acc0[3] = fmaf(a0.w, bb0, acc0[3]); acc1[3] = fmaf(a0.w, bb1, acc1[3]);
            acc0[4] = fmaf(a1.x, bb0, acc0[4]); acc1[4] = fmaf(a1.x, bb1, acc1[4]);
            acc0[5] = fmaf(a1.y, bb0, acc0[5]); acc1[5] = fmaf(a1.y, bb1, acc1[5]);
            acc0[6] = fmaf(a1.z, bb0, acc0[6]); acc1[6] = fmaf(a1.z, bb1, acc1[6]);
            acc0[7] = fmaf(a1.w, bb0, acc0[7]); acc1[7] = fmaf(a1.w, bb1, acc1[7]);
        }
    }

    #pragma unroll
    for (int i = 0; i < 8; ++i) {
        int m = mtile * 32 + r0 + i;
        int s_local = m >> 7, b = m & 127;
        size_t base = (((size_t)dir * chunk_len + s_local) * BATCH + b) * G4 + ntile * 128;
        xw[base + col0] = acc0[i];
        xw[base + col0 + 64] = acc1[i];
    }
}

// ---------------------------------------------------------------------------
// Kernel B: one LSTM step, h@U only (xw precomputed). grid (16,8,2) x 256.
// Thread (g,r,q): float4 of z for gate g, row r, cols ut*32+q*4. k-loop
// unrolled 16 with register prefetch of the next 16 U-float4s (32 loads in
// flight per wave -> covers L2 latency).
// ---------------------------------------------------------------------------
__global__ __launch_bounds__(256) void lstm_step_v13(
    const float* __restrict__ xw_f, const float* __restrict__ xw_b, // [128][1024]
    const float* __restrict__ U_f, const float* __restrict__ U_b,
    const float* __restrict__ h_in, float* __restrict__ h_out,
    float* __restrict__ c_state)
{
    const int rt  = blockIdx.x;
    const int ut  = blockIdx.y;
    const int dir = blockIdx.z;
    const float* __restrict__ U  = dir ? U_b : U_f;
    const float* __restrict__ xw = dir ? xw_b : xw_f;
    const int tid = threadIdx.x;
    const int g = tid >> 6, r = (tid >> 3) & 7, q = tid & 7;

    __shared__ float hs[8][260];
    __shared__ float zs[4][8][32];

    for (int i = tid; i < 2048; i += 256) {
        int rr = i >> 8, k = i & 255;
        hs[rr][k] = h_in[((size_t)dir * BATCH + rt * 8 + rr) * HID + k];
    }
    __syncthreads();

    const int col = g * 256 + ut * 32 + q * 4;
    float4 acc = *(const float4*)&xw[(size_t)(rt * 8 + r) * G4 + col];
    const float4* __restrict__ U4 = (const float4*)(U + col);

    float4 ub[16], un[16];
    #pragma unroll
    for (int j = 0; j < 16; ++j) ub[j] = U4[(size_t)j * 256];
    for (int k0 = 0; k0 < 256; k0 += 16) {
        #pragma unroll
        for (int j = 0; j < 16; ++j)
            un[j] = U4[(size_t)((k0 + 16 + j) & 255) * 256];   // clamped wrap
        #pragma unroll
        for (int j = 0; j < 16; ++j) {
            float hv = hs[r][k0 + j];
            acc.x = fmaf(hv, ub[j].x, acc.x);
            acc.y = fmaf(hv, ub[j].y, acc.y);
            acc.z = fmaf(hv, ub[j].z, acc.z);
            acc.w = fmaf(hv, ub[j].w, acc.w);
        }
        #pragma unroll
        for (int j = 0; j < 16; ++j) ub[j] = un[j];
    }
    *(float4*)&zs[g][r][q * 4] = acc;
    __syncthreads();

    {
        const int r2 = tid >> 5, j2 = tid & 31;
        float zi = zs[0][r2][j2];
        float zf = zs[1][r2][j2];
        float zg = zs[2][r2][j2];
        float zo = zs[3][r2][j2];
        float si = 1.0f / (1.0f + expf(-zi));
        float sf = 1.0f / (1.0f + expf(-zf));
        float tg = tanhf(zg);
        float so = 1.0f / (1.0f + expf(-zo));
        size_t idx = ((size_t)dir * BATCH + rt * 8 + r2) * HID + ut * 32 + j2;
        float cv = fmaf(sf, c_state[idx], si * tg);
        c_state[idx] = cv;
        h_out[idx] = so * tanhf(cv);
    }
}

// ---------------------------------------------------------------------------
// Fallback step kernel (x@W inside, v12 behavior) for tiny workspace.
// ---------------------------------------------------------------------------
__global__ __launch_bounds__(256) void lstm_step_v12(
    const int*   __restrict__ tokens,
    const float* __restrict__ emb_table,
    const float* __restrict__ W_f, const float* __restrict__ U_f, const float* __restrict__ b_f,
    const float* __restrict__ W_b, const float* __restrict__ U_b, const float* __restrict__ b_b,
    const float* __restrict__ h_in, float* __restrict__ h_out,
    float* __restrict__ c_state, int step)
{
    const int rt  = blockIdx.x;
    const int ut  = blockIdx.y;
    const int dir = blockIdx.z;
    const int tid = threadIdx.x;
    const float* __restrict__ W  = dir ? W_b : W_f;
    const float* __restrict__ U  = dir ? U_b : U_f;
    const float* __restrict__ bs = dir ? b_b : b_f;

    __shared__ int   tok[8];
    __shared__ float xs[8][260];
    __shared__ float hs[8][260];
    __shared__ float zs[4][8][32];

    const int tt = dir ? (T_SEQ - 1 - step) : step;
    if (tid < 8) {
        int token = tokens[(rt * 8 + tid) * T_SEQ + tt];
        tok[tid] = (token < 0) ? 0 : (token > 49999 ? 49999 : token);
    }
    __syncthreads();
    for (int i = tid; i < 2048; i += 256) {
        int r = i >> 8, k = i & 255;
        xs[r][k] = emb_table[(size_t)tok[r] * 256 + k];
        hs[r][k] = h_in[((size_t)dir * BATCH + rt * 8 + r) * HID + k];
    }
    __syncthreads();

    const int g = tid >> 6, r = (tid >> 3) & 7, q = tid & 7;
    const int col = g * 256 + ut * 32 + q * 4;
    const float4* __restrict__ W4 = (const float4*)(W + col);
    const float4* __restrict__ U4 = (const float4*)(U + col);
    float4 acc = *(const float4*)(bs + col);
    #pragma unroll 4
    for (int k = 0; k < 256; ++k) {
        float xv = xs[r][k], hv = hs[r][k];
        float4 w = W4[(size_t)k * 256];
        float4 u = U4[(size_t)k * 256];
        acc.x = fmaf(xv, w.x, acc.x); acc.y = fmaf(xv, w.y, acc.y);
        acc.z = fmaf(xv, w.z, acc.z); acc.w = fmaf(xv, w.w, acc.w);
        acc.x = fmaf(hv, u.x, acc.x); acc.y = fmaf(hv, u.y, acc.y);
        acc.z = fmaf(hv, u.z, acc.z); acc.w = fmaf(hv, u.w, acc.w);
    }
    *(float4*)&zs[g][r][q * 4] = acc;
    __syncthreads();
    {
        const int r2 = tid >> 5, j2 = tid & 31;
        float si = 1.0f / (1.0f + expf(-zs[0][r2][j2]));
        float sf = 1.0f / (1.0f + expf(-zs[1][r2][j2]));
        float tg = tanhf(zs[2][r2][j2]);
        float so = 1.0f / (1.0f + expf(-zs[3][r2][j2]));
        size_t idx = ((size_t)dir * BATCH + rt * 8 + r2) * HID + ut * 32 + j2;
        float cv = fmaf(sf, c_state[idx], si * tg);
        c_state[idx] = cv;
        h_out[idx] = so * tanhf(cv);
    }
}

// ---------------------------------------------------------------------------
// Dense + softmax (f32): one block per batch row.
// ---------------------------------------------------------------------------
__global__ __launch_bounds__(64) void dense_softmax_v13(
    const float* __restrict__ h_final,
    const float* __restrict__ W_d, const float* __restrict__ b_d,
    float* __restrict__ out)
{
    const int rrow = blockIdx.x;
    const int cth  = threadIdx.x;
    __shared__ float lg[NCLS];
    if (cth < NCLS) {
        const float* hf = h_final + (size_t)rrow * HID;
        const float* hb = h_final + ((size_t)BATCH + rrow) * HID;
        float s = b_d[cth];
        for (int k = 0; k < HID; ++k) s = fmaf(hf[k], W_d[k * NCLS + cth], s);
        for (int k = 0; k < HID; ++k) s = fmaf(hb[k], W_d[(HID + k) * NCLS + cth], s);
        lg[cth] = s;
    }
    __syncthreads();
    if (cth == 0) {
        float m = lg[0];
        for (int c = 1; c < NCLS; ++c) m = fmaxf(m, lg[c]);
        float e[NCLS]; float ssum = 0.0f;
        for (int c = 0; c < NCLS; ++c) { e[c] = expf(lg[c] - m); ssum += e[c]; }
        float inv = 1.0f / ssum;
        for (int c = 0; c < NCLS; ++c) out[rrow * NCLS + c] = e[c] * inv;
    }
}

extern "C" void kernel_launch(void* const* d_in, const int* in_sizes, int n_in,
                              void* d_out, int out_size, void* d_ws, size_t ws_size,
                              hipStream_t stream)
{
    const int*   tokens = (const int*)d_in[0];
    const float* emb    = (const float*)d_in[1];
    const float* W_f    = (const float*)d_in[2];
    const float* U_f    = (const float*)d_in[3];
    const float* b_f    = (const float*)d_in[4];
    const float* W_b    = (const float*)d_in[5];
    const float* U_b    = (const float*)d_in[6];
    const float* b_b    = (const float*)d_in[7];
    const float* W_d    = (const float*)d_in[8];
    const float* b_d    = (const float*)d_in[9];
    float* out = (float*)d_out;
    float* ws  = (float*)d_ws;

    const size_t HSLOT = (size_t)2 * BATCH * HID;        // 65536 floats
    // pick largest xw chunk that fits: {512 (full), 64, 16}
    int chunk = 0;
    const int cand[3] = {512, 64, 16};
    for (int i = 0; i < 3; ++i) {
        size_t need = ((size_t)2 * cand[i] * BATCH * G4 + 3 * HSLOT) * sizeof(float);
        if (ws_size >= need) { chunk = cand[i]; break; }
    }

    if (chunk == 0) {
        // tiny-ws fallback: v12 monolithic-step path
        float* hbuf0 = ws;
        float* cbuf  = hbuf0 + HSLOT;
        float* hbuf1 = cbuf + HSLOT;
        hipMemsetAsync(hbuf0, 0, 2 * HSLOT * sizeof(float), stream);
        float* hin = hbuf0; float* hout = hbuf1;
        for (int s = 0; s < T_SEQ; ++s) {
            lstm_step_v12<<<dim3(16, 8, 2), 256, 0, stream>>>(
                tokens, emb, W_f, U_f, b_f, W_b, U_b, b_b, hin, hout, cbuf, s);
            float* tmp = hin; hin = hout; hout = tmp;
        }
        dense_softmax_v13<<<dim3(BATCH), 64, 0, stream>>>(hin, W_d, b_d, out);
        return;
    }

    float* xw    = ws;                                    // [2][chunk][128][1024]
    float* hbuf0 = xw + (size_t)2 * chunk * BATCH * G4;
    float* cbuf  = hbuf0 + HSLOT;
    float* hbuf1 = cbuf + HSLOT;
    hipMemsetAsync(hbuf0, 0, 2 * HSLOT * sizeof(float), stream);  // h0 + c0

    float* hin = hbuf0; float* hout = hbuf1;
    for (int c0 = 0; c0 < T_SEQ; c0 += chunk) {
        xw_gemm_v13<<<dim3(chunk * BATCH / 32, 8, 2), 256, 0, stream>>>(
            tokens, emb, W_f, b_f, W_b, b_b, xw, c0, chunk);
        for (int s = c0; s < c0 + chunk; ++s) {
            int sl = s - c0;
            const float* xwf = xw + (size_t)sl * BATCH * G4;
            const float* xwb = xw + ((size_t)chunk + sl) * BATCH * G4;
            lstm_step_v13<<<dim3(16, 8, 2), 256, 0, stream>>>(
                xwf, xwb, U_f, U_b, hin, hout, cbuf);
            float* tmp = hin; hin = hout; hout = tmp;
        }
    }
    dense_softmax_v13<<<dim3(BATCH), 64, 0, stream>>>(hin, W_d, b_d, out);
}